// Round 7
// baseline (99.287 us; speedup 1.0000x reference)
//
#include <hip/hip_runtime.h>
#include <cstdint>

// ---------------------------------------------------------------------------
// H3 block: out = q * S4D( v * Shift(k) ),  q/k/v = W{q,k,v} @ x + b
// GEMM: merged M=1536 x N=16384 x K=512. BM=256 x BN=128, 8 waves (4Mx2N),
//   BK=64, 3 LDS buffers (144 KB), 2-tiles-ahead global_load_lds prefetch,
//   ONE counted s_waitcnt vmcnt(6) + ONE raw s_barrier per K-tile (never
//   drains in main loop), setprio around MFMA clusters, swizzled ds_read_b128.
//   Grid 768 = 3.0 exact rounds over 256 CUs, bijective XCD swizzle.
// S4D + Shift as per-(b,h) chunked MFMA GEMMs (T=64) vs per-h tables stored
//   in pre-swizzled LDS-image layout. Swizzle: 16B slot s -> s ^ (row&7).
// ---------------------------------------------------------------------------

#define DMODEL 512
#define LSEQ 2048

typedef _Float16 half_t;
typedef __attribute__((ext_vector_type(4))) _Float16 half4v;
typedef __attribute__((ext_vector_type(8))) _Float16 half8v;
typedef __attribute__((ext_vector_type(4))) float floatx4;

#define SW(R, c) ((R) * 64 + ((((c) >> 3) ^ ((R) & 7)) << 3) + ((c) & 7))

__device__ __forceinline__ void gload_lds16(const half_t* g, half_t* l) {
  __builtin_amdgcn_global_load_lds(
      (const __attribute__((address_space(1))) uint32_t*)g,
      (__attribute__((address_space(3))) uint32_t*)l, 16, 0, 0);
}

// ---------------- convert W (3 x 512x512) fp32 -> f16 ----------------------
__global__ __launch_bounds__(256) void convert_w(
    const float* __restrict__ Wq, const float* __restrict__ Wk,
    const float* __restrict__ Wv, half_t* __restrict__ W16) {
  int i = blockIdx.x * 256 + threadIdx.x;
  const float* src = (i < 262144) ? Wq : ((i < 524288) ? Wk : Wv);
  int j = i & 262143;
  W16[i] = (half_t)src[j];
}

// ---------------- transpose x (B,D,L) f32 -> xT (B,L,D) f16 ----------------
__global__ __launch_bounds__(256) void transpose_x(
    const float* __restrict__ x, half_t* __restrict__ xT) {
  __shared__ float tile[64][68];
  int b = blockIdx.z;
  int d0 = blockIdx.y * 64;
  int l0 = blockIdx.x * 64;
  int t = threadIdx.x;
  int dy = t >> 4, lx = t & 15;
  const float* xp = x + ((size_t)(b * 512 + d0)) * 2048 + l0;
#pragma unroll
  for (int rr = 0; rr < 4; rr++) {
    float4 v = *(const float4*)(xp + (size_t)(rr * 16 + dy) * 2048 + lx * 4);
    *(float4*)&tile[rr * 16 + dy][lx * 4] = v;
  }
  __syncthreads();
  half_t* op = xT + ((size_t)(b * 2048 + l0)) * 512 + d0;
  int lr = t >> 2, c4 = t & 3;
#pragma unroll
  for (int cc = 0; cc < 2; cc++) {
    int ch = cc * 4 + c4;
    half8v hv;
#pragma unroll
    for (int e = 0; e < 8; e++) hv[e] = (half_t)tile[ch * 8 + e][lr];
    *(half8v*)(op + (size_t)lr * 512 + ch * 8) = hv;
  }
}

// ---------------- per-h table builder (setup folded in) --------------------
__global__ __launch_bounds__(256) void s4d_tables(
    const float* __restrict__ log_dt, const float* __restrict__ A_real,
    const float* __restrict__ A_imag, const float* __restrict__ C_re,
    const float* __restrict__ C_im, const float* __restrict__ shC,
    half_t* __restrict__ Vt, half_t* __restrict__ Et, half_t* __restrict__ Tt,
    half_t* __restrict__ T1t, half_t* __restrict__ T2t,
    float* __restrict__ wt2) {
  __shared__ float aL[32], bL[32], wrL[32], wiL[32], crL[32], ciL[32];
  __shared__ float Kt[64], tapl[64];
  int h = blockIdx.x;
  int tid = threadIdx.x;
  if (tid < 64) { Kt[tid] = 0.f; tapl[tid] = shC[h * 64 + tid]; }
  if (tid < 32) {
    int n = tid, hn = h * 32 + n;
    float dt = expf(log_dt[h]);
    float Ar = -expf(A_real[hn]), Ai = A_imag[hn];
    float a = dt * Ar, b = dt * Ai;
    float ea = expf(a);
    float wr = ea * cosf(b), wi = ea * sinf(b);
    float Am2 = Ar * Ar + Ai * Ai;
    float zr = wr - 1.0f, zi = wi;
    float qr = (zr * Ar + zi * Ai) / Am2;
    float qi = (zi * Ar - zr * Ai) / Am2;
    aL[n] = a; bL[n] = b; wrL[n] = wr; wiL[n] = wi;
    crL[n] = C_re[hn] * qr - C_im[hn] * qi;
    ciL[n] = C_re[hn] * qi + C_im[hn] * qr;
    float e64 = expf(64.0f * a);
    wt2[h * 64 + 2 * n]     = e64 * cosf(64.0f * b);
    wt2[h * 64 + 2 * n + 1] = e64 * sinf(64.0f * b);
  }
  __syncthreads();
  size_t base = (size_t)h * 4096;
  {
    int r = tid >> 2;
    int nb = (tid & 3) * 8;
    float ksum = 0.f;
#pragma unroll
    for (int i = 0; i < 8; i++) {
      int n = nb + i;
      float a = aL[n], b = bL[n];
      float cr = crL[n], ci = ciL[n];
      float er = expf(a * (float)r);
      float w0r = er * cosf(b * (float)r), w0i = er * sinf(b * (float)r);
      ksum += 2.f * (cr * w0r - ci * w0i);
      float wr = wrL[n], wi = wiL[n];
      float w1r = w0r * wr - w0i * wi, w1i = w0r * wi + w0i * wr;
      Et[base + SW(r, 2 * n)]     = (half_t)(2.f * (cr * w1r - ci * w1i));
      Et[base + SW(r, 2 * n + 1)] = (half_t)(-2.f * (cr * w1i + ci * w1r));
      Vt[base + SW(2 * n, 63 - r)]     = (half_t)w0r;
      Vt[base + SW(2 * n + 1, 63 - r)] = (half_t)w0i;
    }
    atomicAdd(&Kt[r], ksum);
  }
  __syncthreads();
#pragma unroll
  for (int e = 0; e < 16; e++) {
    int idx = e * 256 + tid;
    int r = idx >> 6, t = idx & 63;
    int d = r - t;
    size_t a = base + SW(r, t);
    Tt[a]  = (d >= 0) ? (half_t)Kt[d] : (half_t)0.f;
    T1t[a] = (d >= 0) ? (half_t)tapl[d] : (half_t)0.f;
    T2t[a] = (d < 0) ? (half_t)tapl[64 + d] : (half_t)0.f;
  }
}

// ---------------- merged qkv GEMM (256x128, 3-buf, counted vmcnt) ----------
__global__ __launch_bounds__(512) void gemm_qkv(
    const half_t* __restrict__ xT, const half_t* __restrict__ Wstk,
    const float* __restrict__ bq, const float* __restrict__ bk,
    const float* __restrict__ bv, half_t* __restrict__ outq,
    half_t* __restrict__ outk, half_t* __restrict__ outv) {
  extern __shared__ half_t smem[];   // 3 bufs x (A 16384 + B 8192) halfs
  int flat = blockIdx.x;                         // 768 = 8 xcd x 96
  int swz = (flat & 7) * 96 + (flat >> 3);       // bijective XCD swizzle
  int mt = swz % 6, nt = swz / 6;                // mt-inner: XCD shares B-panels
  int m0 = mt * 256, n0 = nt * 128;
  int tid = threadIdx.x;
  int lane = tid & 63, wid = tid >> 6;
  int wm = wid & 3, wn = wid >> 2;               // 4M x 2N wave grid
  int lrow = lane & 15, lg = lane >> 4;
  int rS = tid >> 3;                             // staging row 0..63
  int sS = (tid & 7) ^ (rS & 7);                 // inverse-swizzled src slot

  const half_t* gA = Wstk + (size_t)(m0 + rS) * 512 + sS * 8;
  const half_t* gB = xT + (size_t)(n0 + rS) * 512 + sS * 8;

  floatx4 acc[4][4];
#pragma unroll
  for (int i = 0; i < 4; i++)
#pragma unroll
    for (int j = 0; j < 4; j++) acc[i][j] = (floatx4){0.f, 0.f, 0.f, 0.f};

  // A part ld=0..3 (rows ld*64..), B part ld=0..1
#define STAGE_A(b, kt, ld)                                                    \
  gload_lds16(gA + (size_t)(ld) * 64 * 512 + (kt) * 64,                       \
              smem + (b) * 24576 + ((ld) * 512 + tid) * 8)
#define STAGE_B(b, kt, ld)                                                    \
  gload_lds16(gB + (size_t)(ld) * 64 * 512 + (kt) * 64,                       \
              smem + (b) * 24576 + 16384 + ((ld) * 512 + tid) * 8)

  // prologue: tiles 0,1 in flight (12 loads); wait tile 0 (6 may fly)
  STAGE_A(0, 0, 0); STAGE_A(0, 0, 1); STAGE_A(0, 0, 2); STAGE_A(0, 0, 3);
  STAGE_B(0, 0, 0); STAGE_B(0, 0, 1);
  STAGE_A(1, 1, 0); STAGE_A(1, 1, 1); STAGE_A(1, 1, 2); STAGE_A(1, 1, 3);
  STAGE_B(1, 1, 0); STAGE_B(1, 1, 1);
  asm volatile("s_waitcnt vmcnt(6)" ::: "memory");
  __builtin_amdgcn_s_barrier();
  __builtin_amdgcn_sched_barrier(0);

  int cur = 0;
  for (int t = 0; t < 8; t++) {
    const half_t* Ab = smem + cur * 24576;
    const half_t* Bb = Ab + 16384;
    int wb = cur + 2; if (wb >= 3) wb -= 3;      // buffer for tile t+2

    // ---- phase 0: B frags (held all tile) + A frags mi 0,1 ----
    half8v bf[4][2], af[2][2];
#pragma unroll
    for (int nj = 0; nj < 4; nj++) {
      int rb = wn * 64 + nj * 16 + lrow;
#pragma unroll
      for (int ks = 0; ks < 2; ks++)
        bf[nj][ks] = *(const half8v*)(Bb + rb * 64 + (((ks * 4 + lg) ^ (rb & 7)) << 3));
    }
#pragma unroll
    for (int i = 0; i < 2; i++) {
      int ra = wm * 64 + i * 16 + lrow;
#pragma unroll
      for (int ks = 0; ks < 2; ks++)
        af[i][ks] = *(const half8v*)(Ab + ra * 64 + (((ks * 4 + lg) ^ (ra & 7)) << 3));
    }
    if (t < 6) { STAGE_A(wb, t + 2, 0); STAGE_A(wb, t + 2, 1); STAGE_A(wb, t + 2, 2); }
    __builtin_amdgcn_s_setprio(1);
#pragma unroll
    for (int i = 0; i < 2; i++)
#pragma unroll
      for (int nj = 0; nj < 4; nj++)
#pragma unroll
        for (int ks = 0; ks < 2; ks++)
          acc[i][nj] = __builtin_amdgcn_mfma_f32_16x16x32_f16(af[i][ks], bf[nj][ks],
                                                              acc[i][nj], 0, 0, 0);
    __builtin_amdgcn_s_setprio(0);

    // ---- phase 1: A frags mi 2,3 ----
#pragma unroll
    for (int i = 0; i < 2; i++) {
      int ra = wm * 64 + (2 + i) * 16 + lrow;
#pragma unroll
      for (int ks = 0; ks < 2; ks++)
        af[i][ks] = *(const half8v*)(Ab + ra * 64 + (((ks * 4 + lg) ^ (ra & 7)) << 3));
    }
    if (t < 6) { STAGE_A(wb, t + 2, 3); STAGE_B(wb, t + 2, 0); STAGE_B(wb, t + 2, 1); }
    __builtin_amdgcn_s_setprio(1);
#pragma unroll
    for (int i = 0; i < 2; i++)
#pragma unroll
      for (int nj = 0; nj < 4; nj++)
#pragma unroll
        for (int ks = 0; ks < 2; ks++)
          acc[2 + i][nj] = __builtin_amdgcn_mfma_f32_16x16x32_f16(af[i][ks], bf[nj][ks],
                                                                  acc[2 + i][nj], 0, 0, 0);
    __builtin_amdgcn_s_setprio(0);

    // counted wait: tile t+1's 6 loads (oldest) retired; t+2's 6 stay in flight
    if (t < 6)       asm volatile("s_waitcnt vmcnt(6)" ::: "memory");
    else if (t == 6) asm volatile("s_waitcnt vmcnt(0)" ::: "memory");
    __builtin_amdgcn_s_barrier();
    __builtin_amdgcn_sched_barrier(0);
    cur = cur + 1; if (cur >= 3) cur -= 3;
  }
#undef STAGE_A
#undef STAGE_B

  // epilogue: D col = lane&15 (n), row = 4*(lane>>4)+reg (m). z uniform.
  int z = m0 >> 9;
  const float* bias = (z == 0) ? bq : ((z == 1) ? bk : bv);
  half_t* outp = (z == 0) ? outq : ((z == 1) ? outk : outv);
#pragma unroll
  for (int mi = 0; mi < 4; mi++) {
    int d = (m0 + wm * 64 + mi * 16 + 4 * lg) & 511;
#pragma unroll
    for (int nj = 0; nj < 4; nj++) {
      int n = n0 + wn * 64 + nj * 16 + lrow;
      int b = n >> 11, l = n & 2047;
#pragma unroll
      for (int reg = 0; reg < 4; reg++) {
        float val = acc[mi][nj][reg] + bias[d + reg];
        size_t bhbase = ((size_t)(b * 512 + d + reg)) * 2048;
        if (z == 0) {
          outp[bhbase + l] = (half_t)val;        // q: linear (b,h,l)
        } else {                                  // k,v: swizzled LDS image
          int jj = l >> 6, c = l & 63;
          outp[bhbase + SW(jj, c)] = (half_t)val;
        }
      }
    }
  }
}

// ---------------- fused Shift + S4D + final q-multiply ---------------------
__global__ __launch_bounds__(256) void s4d_main(
    const half_t* __restrict__ kimg, const half_t* __restrict__ vimg,
    const half_t* __restrict__ T1t, const half_t* __restrict__ T2t,
    const half_t* __restrict__ Vt, const half_t* __restrict__ Et,
    const half_t* __restrict__ Tt, const float* __restrict__ wt2,
    const float* __restrict__ shD, const float* __restrict__ s4D,
    const half_t* __restrict__ qbuf, float* __restrict__ outp) {
  __shared__ half_t kl[33 * 64];
  __shared__ half_t vg[32 * 64];
  __shared__ half_t uh[32 * 64];
  __shared__ half_t tab0[64 * 64];
  __shared__ half_t tab1[64 * 64];
  __shared__ half_t tab2[64 * 64];
  __shared__ float SG[32 * 66];
  int bh = blockIdx.x;
  int h = bh & 511;
  int tid = threadIdx.x;
  int lane = tid & 63, wid = tid >> 6;
  int lrow = lane & 15, lg = lane >> 4;
  int mi = wid & 1;
  int ri0 = wid >> 1;

  {
    const half_t* kp = kimg + (size_t)bh * 2048;
    const half_t* vp = vimg + (size_t)bh * 2048;
    size_t tb = (size_t)h * 4096;
    gload_lds16(kp + wid * 512 + lane * 8, kl + 64 + wid * 512);
    gload_lds16(vp + wid * 512 + lane * 8, vg + wid * 512);
#pragma unroll
    for (int i = 0; i < 2; i++) {
      int c = wid * 2 + i;
      gload_lds16(T1t + tb + c * 512 + lane * 8, tab0 + c * 512);
      gload_lds16(T2t + tb + c * 512 + lane * 8, tab1 + c * 512);
      gload_lds16(Vt + tb + c * 512 + lane * 8, tab2 + c * 512);
    }
  }
  if (tid < 8) {
    half8v zz = {(_Float16)0, (_Float16)0, (_Float16)0, (_Float16)0,
                 (_Float16)0, (_Float16)0, (_Float16)0, (_Float16)0};
    *(half8v*)(kl + tid * 8) = zz;
  }
  float sDsh = shD[h];
  float sD4 = s4D[h];
  __syncthreads();

#define LDF(base, r, ks, key) \
  (*(const half8v*)((base) + (r) * 64 + (((ks) * 4 + lg) ^ (key)) * 8))

  floatx4 acc[2];
  acc[0] = (floatx4){0.f, 0.f, 0.f, 0.f};
  acc[1] = (floatx4){0.f, 0.f, 0.f, 0.f};
  {
    int jA = mi * 16 + lrow;
    int key1 = lrow & 7, key2 = (lrow + 7) & 7;
#pragma unroll
    for (int ks = 0; ks < 2; ks++) {
      half8v a1 = LDF(kl, 1 + jA, ks, key1);
      half8v a2 = LDF(kl, jA, ks, key2);
#pragma unroll
      for (int tt = 0; tt < 2; tt++) {
        int rb = (ri0 + tt * 2) * 16 + lrow;
        half8v b1 = LDF(tab0, rb, ks, lrow & 7);
        half8v b2 = LDF(tab1, rb, ks, lrow & 7);
        acc[tt] = __builtin_amdgcn_mfma_f32_16x16x32_f16(a1, b1, acc[tt], 0, 0, 0);
        acc[tt] = __builtin_amdgcn_mfma_f32_16x16x32_f16(a2, b2, acc[tt], 0, 0, 0);
      }
    }
  }
#pragma unroll
  for (int tt = 0; tt < 2; tt++) {
#pragma unroll
    for (int reg = 0; reg < 4; reg++) {
      int j = mi * 16 + 4 * lg + reg;
      int r = (ri0 + tt * 2) * 16 + lrow;
      int cph = (((r >> 3) ^ (j & 7)) << 3) + (r & 7);
      float kvv = (float)kl[(1 + j) * 64 + cph];
      float vvv = (float)vg[j * 64 + cph];
      uh[j * 64 + cph] = (half_t)(vvv * (acc[tt][reg] + sDsh * kvv));
    }
  }
  __syncthreads();

  {
    size_t tb = (size_t)h * 4096;
#pragma unroll
    for (int i = 0; i < 2; i++) {
      int c = wid * 2 + i;
      gload_lds16(Et + tb + c * 512 + lane * 8, tab0 + c * 512);
      gload_lds16(Tt + tb + c * 512 + lane * 8, tab1 + c * 512);
    }
  }

  acc[0] = (floatx4){0.f, 0.f, 0.f, 0.f};
  acc[1] = (floatx4){0.f, 0.f, 0.f, 0.f};
#pragma unroll
  for (int ks = 0; ks < 2; ks++) {
    half8v a = LDF(uh, mi * 16 + lrow, ks, lrow & 7);
#pragma unroll
    for (int tt = 0; tt < 2; tt++) {
      int rb = (ri0 + tt * 2) * 16 + lrow;
      half8v b = LDF(tab2, rb, ks, lrow & 7);
      acc[tt] = __builtin_amdgcn_mfma_f32_16x16x32_f16(a, b, acc[tt], 0, 0, 0);
    }
  }
#pragma unroll
  for (int tt = 0; tt < 2; tt++) {
    int ri = ri0 + tt * 2;
#pragma unroll
    for (int reg = 0; reg < 4; reg++) {
      int j = mi * 16 + 4 * lg + reg;
      SG[j * 66 + ri * 16 + lrow] = acc[tt][reg];
    }
  }
  __syncthreads();

  if (tid < 32) {
    int n = tid;
    float wTr = wt2[h * 64 + 2 * n], wTi = wt2[h * 64 + 2 * n + 1];
    float gr = 0.f, gi = 0.f;
    for (int j = 0; j < 32; j++) {
      float tr = SG[j * 66 + 2 * n], ti = SG[j * 66 + 2 * n + 1];
      SG[j * 66 + 2 * n] = gr; SG[j * 66 + 2 * n + 1] = gi;
      float nr = wTr * gr - wTi * gi + tr;
      gi = wTr * gi + wTi * gr + ti;
      gr = nr;
    }
  }
  __syncthreads();

  {
    int j = tid >> 3, s = tid & 7;
    half8v g;
#pragma unroll
    for (int i = 0; i < 8; i++) g[i] = (half_t)SG[j * 66 + s * 8 + i];
    *(half8v*)(vg + j * 64 + (s ^ (j & 7)) * 8) = g;
  }
  __syncthreads();

  acc[0] = (floatx4){0.f, 0.f, 0.f, 0.f};
  acc[1] = (floatx4){0.f, 0.f, 0.f, 0.f};
#pragma unroll
  for (int ks = 0; ks < 2; ks++) {
    half8v ag = LDF(vg, mi * 16 + lrow, ks, lrow & 7);
    half8v au = LDF(uh, mi * 16 + lrow, ks, lrow & 7);
#pragma unroll
    for (int tt = 0; tt < 2; tt++) {
      int rb = (ri0 + tt * 2) * 16 + lrow;
      half8v be = LDF(tab0, rb, ks, lrow & 7);
      half8v bt = LDF(tab1, rb, ks, lrow & 7);
      acc[tt] = __builtin_amdgcn_mfma_f32_16x16x32_f16(ag, be, acc[tt], 0, 0, 0);
      acc[tt] = __builtin_amdgcn_mfma_f32_16x16x32_f16(au, bt, acc[tt], 0, 0, 0);
    }
  }
#pragma unroll
  for (int tt = 0; tt < 2; tt++) {
#pragma unroll
    for (int reg = 0; reg < 4; reg++) {
      int j = mi * 16 + 4 * lg + reg;
      int r = (ri0 + tt * 2) * 16 + lrow;
      int cph = (((r >> 3) ^ (j & 7)) << 3) + (r & 7);
      SG[j * 64 + r] = acc[tt][reg] + sD4 * (float)uh[j * 64 + cph];
    }
  }
  __syncthreads();

  {
    const half_t* qp = qbuf + (size_t)bh * 2048;
    float* op = outp + (size_t)bh * 2048;
    half8v qv = *(const half8v*)(qp + tid * 8);
    float4 o0, o1;
    o0.x = (float)qv[0] * SG[tid * 8 + 0];
    o0.y = (float)qv[1] * SG[tid * 8 + 1];
    o0.z = (float)qv[2] * SG[tid * 8 + 2];
    o0.w = (float)qv[3] * SG[tid * 8 + 3];
    o1.x = (float)qv[4] * SG[tid * 8 + 4];
    o1.y = (float)qv[5] * SG[tid * 8 + 5];
    o1.z = (float)qv[6] * SG[tid * 8 + 6];
    o1.w = (float)qv[7] * SG[tid * 8 + 7];
    *(float4*)(op + tid * 8) = o0;
    *(float4*)(op + tid * 8 + 4) = o1;
  }
#undef LDF
}

// ---------------------------------------------------------------------------
extern "C" void kernel_launch(void* const* d_in, const int* in_sizes, int n_in,
                              void* d_out, int out_size, void* d_ws, size_t ws_size,
                              hipStream_t stream) {
  const float* x      = (const float*)d_in[0];
  const float* Wq     = (const float*)d_in[1];
  const float* bq     = (const float*)d_in[2];
  const float* Wk     = (const float*)d_in[3];
  const float* bk     = (const float*)d_in[4];
  const float* Wv     = (const float*)d_in[5];
  const float* bv     = (const float*)d_in[6];
  const float* shC    = (const float*)d_in[7];
  const float* shD    = (const float*)d_in[8];
  const float* log_dt = (const float*)d_in[9];
  const float* A_real = (const float*)d_in[10];
  const float* A_imag = (const float*)d_in[11];
  const float* C_re   = (const float*)d_in[12];
  const float* C_im   = (const float*)d_in[13];
  const float* s4D    = (const float*)d_in[14];
  float* out = (float*)d_out;
  half_t* wsh = (half_t*)d_ws;

  half_t* qbuf = wsh;                         // 8388608 halfs (linear)
  half_t* kbuf = wsh + 8388608;               // 8388608 (swizzled image)
  half_t* vbuf = wsh + 16777216;              // 8388608 (swizzled image)
  half_t* xT16 = wsh + 25165824;              // 8388608
  half_t* W16  = wsh + 33554432;              // 786432
  half_t* Vt   = wsh + 34340864;              // 2097152 (swizzled image)
  half_t* Et   = wsh + 36438016;              // 2097152
  half_t* Tt   = wsh + 38535168;              // 2097152
  half_t* T1t  = wsh + 40632320;              // 2097152
  half_t* T2t  = wsh + 42729472;              // 2097152
  float*  wt2  = (float*)(wsh + 44826624);    // 32768 f32

  hipFuncSetAttribute((const void*)gemm_qkv,
                      hipFuncAttributeMaxDynamicSharedMemorySize, 147456);

  convert_w<<<3072, 256, 0, stream>>>(Wq, Wk, Wv, W16);
  transpose_x<<<dim3(32, 8, 8), 256, 0, stream>>>(x, xT16);
  s4d_tables<<<512, 256, 0, stream>>>(log_dt, A_real, A_imag, C_re, C_im, shC,
                                      Vt, Et, Tt, T1t, T2t, wt2);
  gemm_qkv<<<dim3(768), 512, 147456, stream>>>(xT16, W16, bq, bk, bv,
                                               qbuf, kbuf, vbuf);
  s4d_main<<<4096, 256, 0, stream>>>(kbuf, vbuf, T1t, T2t, Vt, Et, Tt,
                                     wt2, shD, s4D, qbuf, out);
}

// Round 8
// 86.131 us; speedup vs baseline: 1.1527x; 1.1527x over previous
//
#include <hip/hip_runtime.h>
#include <cstdint>

// ---------------------------------------------------------------------------
// H3 block: out = q * S4D( v * Shift(k) ),  q/k/v = W{q,k,v} @ x + b
// prep   : ONE kernel, 3 concurrent sections (tables | transpose | convert_w)
// gemm   : merged M=1536 x N=16384 x K=512, 128x128, BK=64, gload_lds(16B),
//          swizzled ds_read_b128, LDS epilogue -> coalesced half8 stores
// s4d    : one block per head h (512 blocks = 2/CU, fully resident), 8-batch
//          loop; 5 tables LDS-resident; k/v double-buffered one batch ahead
//          with counted vmcnt(2); raw s_barrier + lgkmcnt waits (no drains).
// Swizzle: within a 64-half row R, 16B slot s -> s ^ (R&7).
// ---------------------------------------------------------------------------

#define DMODEL 512
#define LSEQ 2048

typedef _Float16 half_t;
typedef __attribute__((ext_vector_type(4))) _Float16 half4v;
typedef __attribute__((ext_vector_type(8))) _Float16 half8v;
typedef __attribute__((ext_vector_type(4))) float floatx4;

#define SW(R, c) ((R) * 64 + ((((c) >> 3) ^ ((R) & 7)) << 3) + ((c) & 7))

__device__ __forceinline__ void gload_lds16(const half_t* g, half_t* l) {
  __builtin_amdgcn_global_load_lds(
      (const __attribute__((address_space(1))) uint32_t*)g,
      (__attribute__((address_space(3))) uint32_t*)l, 16, 0, 0);
}

#define WAIT_LGKM_BAR()                                   \
  do {                                                    \
    asm volatile("s_waitcnt lgkmcnt(0)" ::: "memory");    \
    __builtin_amdgcn_s_barrier();                         \
    __builtin_amdgcn_sched_barrier(0);                    \
  } while (0)

// ---------------- merged prep: tables | transpose | convert ---------------
__global__ __launch_bounds__(256) void prep(
    const float* __restrict__ x, const float* __restrict__ Wq,
    const float* __restrict__ Wk, const float* __restrict__ Wv,
    const float* __restrict__ log_dt, const float* __restrict__ A_real,
    const float* __restrict__ A_imag, const float* __restrict__ C_re,
    const float* __restrict__ C_im, const float* __restrict__ shC,
    half_t* __restrict__ xT, half_t* __restrict__ W16,
    half_t* __restrict__ Vt, half_t* __restrict__ Et, half_t* __restrict__ Tt,
    half_t* __restrict__ T1t, half_t* __restrict__ T2t,
    float* __restrict__ wt2) {
  __shared__ float tile[64][68];                 // transpose section
  __shared__ float aL[32], bL[32], wrL[32], wiL[32], crL[32], ciL[32];
  __shared__ float Kt[64], tapl[64];
  int bid = blockIdx.x;
  int tid = threadIdx.x;

  if (bid < 512) {
    // ---------------- s4d tables for head h = bid ----------------
    int h = bid;
    if (tid < 64) { Kt[tid] = 0.f; tapl[tid] = shC[h * 64 + tid]; }
    if (tid < 32) {
      int n = tid, hn = h * 32 + n;
      float dt = expf(log_dt[h]);
      float Ar = -expf(A_real[hn]), Ai = A_imag[hn];
      float a = dt * Ar, b = dt * Ai;
      float ea = expf(a);
      float wr = ea * cosf(b), wi = ea * sinf(b);
      float Am2 = Ar * Ar + Ai * Ai;
      float zr = wr - 1.0f, zi = wi;
      float qr = (zr * Ar + zi * Ai) / Am2;
      float qi = (zi * Ar - zr * Ai) / Am2;
      aL[n] = a; bL[n] = b; wrL[n] = wr; wiL[n] = wi;
      crL[n] = C_re[hn] * qr - C_im[hn] * qi;
      ciL[n] = C_re[hn] * qi + C_im[hn] * qr;
      float e64 = expf(64.0f * a);
      wt2[h * 64 + 2 * n]     = e64 * cosf(64.0f * b);
      wt2[h * 64 + 2 * n + 1] = e64 * sinf(64.0f * b);
    }
    __syncthreads();
    size_t base = (size_t)h * 4096;
    {
      int r = tid >> 2;
      int nb = (tid & 3) * 8;
      float ksum = 0.f;
#pragma unroll
      for (int i = 0; i < 8; i++) {
        int n = nb + i;
        float a = aL[n], b = bL[n];
        float cr = crL[n], ci = ciL[n];
        float er = expf(a * (float)r);
        float w0r = er * cosf(b * (float)r), w0i = er * sinf(b * (float)r);
        ksum += 2.f * (cr * w0r - ci * w0i);
        float wr = wrL[n], wi = wiL[n];
        float w1r = w0r * wr - w0i * wi, w1i = w0r * wi + w0i * wr;
        Et[base + SW(r, 2 * n)]     = (half_t)(2.f * (cr * w1r - ci * w1i));
        Et[base + SW(r, 2 * n + 1)] = (half_t)(-2.f * (cr * w1i + ci * w1r));
        Vt[base + SW(2 * n, 63 - r)]     = (half_t)w0r;
        Vt[base + SW(2 * n + 1, 63 - r)] = (half_t)w0i;
      }
      atomicAdd(&Kt[r], ksum);
    }
    __syncthreads();
#pragma unroll
    for (int e = 0; e < 16; e++) {
      int idx = e * 256 + tid;
      int r = idx >> 6, t = idx & 63;
      int d = r - t;
      size_t a = base + SW(r, t);
      Tt[a]  = (d >= 0) ? (half_t)Kt[d] : (half_t)0.f;
      T1t[a] = (d >= 0) ? (half_t)tapl[d] : (half_t)0.f;
      T2t[a] = (d < 0) ? (half_t)tapl[64 + d] : (half_t)0.f;
    }
  } else if (bid < 2560) {
    // ---------------- transpose x (64x64 tiles) ----------------
    int i = bid - 512;
    int b = i >> 8, rem = i & 255;
    int d0 = (rem >> 5) * 64, l0 = (rem & 31) * 64;
    int dy = tid >> 4, lx = tid & 15;
    const float* xp = x + ((size_t)(b * 512 + d0)) * 2048 + l0;
#pragma unroll
    for (int rr = 0; rr < 4; rr++) {
      float4 v = *(const float4*)(xp + (size_t)(rr * 16 + dy) * 2048 + lx * 4);
      *(float4*)&tile[rr * 16 + dy][lx * 4] = v;
    }
    __syncthreads();
    half_t* op = xT + ((size_t)(b * 2048 + l0)) * 512 + d0;
    int lr = tid >> 2, c4 = tid & 3;
#pragma unroll
    for (int cc = 0; cc < 2; cc++) {
      int ch = cc * 4 + c4;
      half8v hv;
#pragma unroll
      for (int e = 0; e < 8; e++) hv[e] = (half_t)tile[ch * 8 + e][lr];
      *(half8v*)(op + (size_t)lr * 512 + ch * 8) = hv;
    }
  } else {
    // ---------------- convert W (grid-stride x6) ----------------
    int base = (bid - 2560) * 256 + tid;
#pragma unroll
    for (int it = 0; it < 6; it++) {
      int i = base + it * 131072;
      const float* src = (i < 262144) ? Wq : ((i < 524288) ? Wk : Wv);
      W16[i] = (half_t)src[i & 262143];
    }
  }
}

// ---------------- merged qkv GEMM (128x128, BK=64, LDS epilogue) -----------
__global__ __launch_bounds__(256) void gemm_qkv(
    const half_t* __restrict__ xT, const half_t* __restrict__ Wstk,
    const float* __restrict__ bq, const float* __restrict__ bk,
    const float* __restrict__ bv, half_t* __restrict__ outq,
    half_t* __restrict__ outk, half_t* __restrict__ outv) {
  __shared__ half_t smem[16384];   // As 8192 | Bs 8192; reused as C 128x128
  half_t* As = smem;
  half_t* Bs = smem + 8192;
  int flat = blockIdx.x;                         // 1536 = 8 xcd x 192
  int swz = (flat & 7) * 192 + (flat >> 3);      // XCD chunk swizzle
  int nt = swz / 12, mt = swz - nt * 12;
  int n0 = nt * 128, m0 = mt * 128;
  int tid = threadIdx.x;
  int lane = tid & 63, wid = tid >> 6;
  int wr = wid >> 1, wc = wid & 1;
  int lrow = lane & 15, lg = lane >> 4;
  int rsub = lane >> 3, ssub = lane & 7;
  int gslot = ssub ^ rsub;                       // inverse-swizzled source slot

  floatx4 acc[4][4];
#pragma unroll
  for (int i = 0; i < 4; i++)
#pragma unroll
    for (int j = 0; j < 4; j++) acc[i][j] = (floatx4){0.f, 0.f, 0.f, 0.f};

  const half_t* gA = Wstk + (size_t)(m0 + wid * 32 + rsub) * 512 + gslot * 8;
  const half_t* gB = xT + (size_t)(n0 + wid * 32 + rsub) * 512 + gslot * 8;

  for (int kk = 0; kk < 512; kk += 64) {
#pragma unroll
    for (int i = 0; i < 4; i++) {
      int c = wid * 4 + i;                       // 1KB chunk, rows c*8..c*8+7
      gload_lds16(gA + (size_t)i * 8 * 512 + kk, As + c * 512);
      gload_lds16(gB + (size_t)i * 8 * 512 + kk, Bs + c * 512);
    }
    __syncthreads();
#pragma unroll
    for (int h = 0; h < 2; h++) {
      half8v af[4], bf[4];
#pragma unroll
      for (int i = 0; i < 4; i++) {
        int r = wr * 64 + i * 16 + lrow;
        af[i] = *(const half8v*)(As + r * 64 + ((h * 4 + lg) ^ (r & 7)) * 8);
      }
#pragma unroll
      for (int j = 0; j < 4; j++) {
        int r = wc * 64 + j * 16 + lrow;
        bf[j] = *(const half8v*)(Bs + r * 64 + ((h * 4 + lg) ^ (r & 7)) * 8);
      }
#pragma unroll
      for (int i = 0; i < 4; i++)
#pragma unroll
        for (int j = 0; j < 4; j++)
          acc[i][j] = __builtin_amdgcn_mfma_f32_16x16x32_f16(af[i], bf[j],
                                                             acc[i][j], 0, 0, 0);
    }
    __syncthreads();
  }

  // ---- epilogue via LDS: frags -> swizzled C tile -> coalesced stores ----
  int z = m0 >> 9;                               // uniform per block
  const float* bias = (z == 0) ? bq : ((z == 1) ? bk : bv);
  half_t* smemC = smem;                          // 128 x 128 halfs, slot^=(d&15)
#pragma unroll
  for (int i = 0; i < 4; i++) {
    int dl = wr * 64 + i * 16 + 4 * lg;
    float4 b4 = *(const float4*)&bias[(m0 + dl) & 511];
#pragma unroll
    for (int j = 0; j < 4; j++) {
      int ll = wc * 64 + j * 16 + lrow;
#pragma unroll
      for (int reg = 0; reg < 4; reg++) {
        int d = dl + reg;
        float val = acc[i][j][reg] + ((const float*)&b4)[reg];
        smemC[d * 128 + (((ll >> 3) ^ (d & 15)) << 3) + (ll & 7)] = (half_t)val;
      }
    }
  }
  __syncthreads();
  {
    int t4 = tid >> 4, ch = tid & 15;
    int b = n0 >> 11, l0 = n0 & 2047;
    half_t* outp = (z == 0) ? outq : ((z == 1) ? outk : outv);
#pragma unroll
    for (int rep = 0; rep < 8; rep++) {
      int d = rep * 16 + t4;
      half8v v = *(const half8v*)(smemC + d * 128 + ((ch ^ (d & 15)) << 3));
      size_t rowb = ((size_t)(b * 512 + ((m0 + d) & 511))) * 2048;
      if (z == 0) {
        *(half8v*)(outp + rowb + l0 + ch * 8) = v;       // q: linear
      } else {                                            // k,v: swizzled image
        int j = (l0 >> 6) + (ch >> 3);
        int s = ch & 7;
        *(half8v*)(outp + rowb + j * 64 + ((s ^ (j & 7)) << 3)) = v;
      }
    }
  }
}

// ---------------- fused Shift + S4D per head, 8-batch loop -----------------
__global__ __launch_bounds__(256) void s4d_main(
    const half_t* __restrict__ kimg, const half_t* __restrict__ vimg,
    const half_t* __restrict__ T1t, const half_t* __restrict__ T2t,
    const half_t* __restrict__ Vt, const half_t* __restrict__ Et,
    const half_t* __restrict__ Tt, const float* __restrict__ wt2,
    const float* __restrict__ shD, const float* __restrict__ s4D,
    const half_t* __restrict__ qbuf, float* __restrict__ outp) {
  __shared__ half_t tabs[5][4096];  // T1 T2 V E T (resident all batches)
  __shared__ half_t kl[2][33 * 64]; // row 0 zeros; row 1+j = k chunk j
  __shared__ half_t vg[2][32 * 64]; // v, later G~ (f16)
  __shared__ half_t uh[32 * 64];    // u = v * shift(k)
  __shared__ float SG[32 * 66];     // scan states, then flat y[2048]
  int h = blockIdx.x;
  int tid = threadIdx.x;
  int lane = tid & 63, wid = tid >> 6;
  int lrow = lane & 15, lg = lane >> 4;
  int mi = wid & 1, ri0 = wid >> 1;

  // ---- prologue: stage all 5 tables + batch-0 k/v (12 gloads per wave) ----
  {
    size_t tb = (size_t)h * 4096;
#pragma unroll
    for (int i = 0; i < 2; i++) {
      int c = wid * 2 + i;
      gload_lds16(T1t + tb + c * 512 + lane * 8, &tabs[0][c * 512]);
      gload_lds16(T2t + tb + c * 512 + lane * 8, &tabs[1][c * 512]);
      gload_lds16(Vt  + tb + c * 512 + lane * 8, &tabs[2][c * 512]);
      gload_lds16(Et  + tb + c * 512 + lane * 8, &tabs[3][c * 512]);
      gload_lds16(Tt  + tb + c * 512 + lane * 8, &tabs[4][c * 512]);
    }
    gload_lds16(kimg + (size_t)h * 2048 + wid * 512 + lane * 8,
                &kl[0][64 + wid * 512]);
    gload_lds16(vimg + (size_t)h * 2048 + wid * 512 + lane * 8,
                &vg[0][wid * 512]);
  }
  if (tid < 16) {
    half8v zz = {(_Float16)0, (_Float16)0, (_Float16)0, (_Float16)0,
                 (_Float16)0, (_Float16)0, (_Float16)0, (_Float16)0};
    *(half8v*)(&kl[tid >> 3][(tid & 7) * 8]) = zz;
  }
  float sDsh = shD[h];
  float sD4 = s4D[h];
  float wTr = wt2[h * 64 + 2 * (tid & 31)];
  float wTi = wt2[h * 64 + 2 * (tid & 31) + 1];
  const half_t* t1 = tabs[0];
  const half_t* t2 = tabs[1];
  const half_t* tV = tabs[2];
  const half_t* tE = tabs[3];
  const half_t* tT = tabs[4];

#define LDF(base, r, ks, key) \
  (*(const half8v*)((base) + (r) * 64 + (((ks) * 4 + lg) ^ (key)) * 8))

  int cur = 0;
  for (int bi = 0; bi < 8; bi++) {
    // issue next batch's k/v (2 gloads/wave), then counted wait for current
    if (bi < 7) {
      size_t nb = (size_t)((bi + 1) * 512 + h) * 2048;
      gload_lds16(kimg + nb + wid * 512 + lane * 8, &kl[cur ^ 1][64 + wid * 512]);
      gload_lds16(vimg + nb + wid * 512 + lane * 8, &vg[cur ^ 1][wid * 512]);
      asm volatile("s_waitcnt vmcnt(2) lgkmcnt(0)" ::: "memory");
    } else {
      asm volatile("s_waitcnt vmcnt(0) lgkmcnt(0)" ::: "memory");
    }
    __builtin_amdgcn_s_barrier();
    __builtin_amdgcn_sched_barrier(0);

    const half_t* klc = kl[cur];
    half_t* vgc = vg[cur];
    floatx4 acc[2];

    // ---- shift: shift[j][r] = k_j @ T1' + k_{j-1} @ T2' ----
    acc[0] = (floatx4){0.f, 0.f, 0.f, 0.f};
    acc[1] = (floatx4){0.f, 0.f, 0.f, 0.f};
    {
      int jA = mi * 16 + lrow;
      int key1 = lrow & 7, key2 = (lrow + 7) & 7;
#pragma unroll
      for (int ks = 0; ks < 2; ks++) {
        half8v a1 = LDF(klc, 1 + jA, ks, key1);
        half8v a2 = LDF(klc, jA, ks, key2);
#pragma unroll
        for (int tt = 0; tt < 2; tt++) {
          int rb = (ri0 + tt * 2) * 16 + lrow;
          half8v b1 = LDF(t1, rb, ks, lrow & 7);
          half8v b2 = LDF(t2, rb, ks, lrow & 7);
          acc[tt] = __builtin_amdgcn_mfma_f32_16x16x32_f16(a1, b1, acc[tt], 0, 0, 0);
          acc[tt] = __builtin_amdgcn_mfma_f32_16x16x32_f16(a2, b2, acc[tt], 0, 0, 0);
        }
      }
    }
    // u = v * (shift + shD*k)
#pragma unroll
    for (int tt = 0; tt < 2; tt++) {
#pragma unroll
      for (int reg = 0; reg < 4; reg++) {
        int j = mi * 16 + 4 * lg + reg;
        int r = (ri0 + tt * 2) * 16 + lrow;
        int cph = (((r >> 3) ^ (j & 7)) << 3) + (r & 7);
        float kvv = (float)klc[(1 + j) * 64 + cph];
        float vvv = (float)vgc[j * 64 + cph];
        uh[j * 64 + cph] = (half_t)(vvv * (acc[tt][reg] + sDsh * kvv));
      }
    }
    WAIT_LGKM_BAR();

    // ---- S phase: S[j][m] = u_j @ V' ----
    acc[0] = (floatx4){0.f, 0.f, 0.f, 0.f};
    acc[1] = (floatx4){0.f, 0.f, 0.f, 0.f};
#pragma unroll
    for (int ks = 0; ks < 2; ks++) {
      half8v a = LDF(uh, mi * 16 + lrow, ks, lrow & 7);
#pragma unroll
      for (int tt = 0; tt < 2; tt++) {
        int rb = (ri0 + tt * 2) * 16 + lrow;
        half8v b = LDF(tV, rb, ks, lrow & 7);
        acc[tt] = __builtin_amdgcn_mfma_f32_16x16x32_f16(a, b, acc[tt], 0, 0, 0);
      }
    }
#pragma unroll
    for (int tt = 0; tt < 2; tt++) {
      int ri = ri0 + tt * 2;
#pragma unroll
      for (int reg = 0; reg < 4; reg++) {
        int j = mi * 16 + 4 * lg + reg;
        SG[j * 66 + ri * 16 + lrow] = acc[tt][reg];
      }
    }
    WAIT_LGKM_BAR();

    // ---- scan over chunks (thread n), SG[j] <- G_{j-1} ----
    if (tid < 32) {
      int n = tid;
      float gr = 0.f, gi = 0.f;
      for (int j = 0; j < 32; j++) {
        float tr = SG[j * 66 + 2 * n], ti = SG[j * 66 + 2 * n + 1];
        SG[j * 66 + 2 * n] = gr; SG[j * 66 + 2 * n + 1] = gi;
        float nr = wTr * gr - wTi * gi + tr;
        gi = wTr * gi + wTi * gr + ti;
        gr = nr;
      }
    }
    WAIT_LGKM_BAR();

    // ---- convert G (f32) -> f16 into vg[cur] (v already consumed) ----
    {
      int j = tid >> 3, s = tid & 7;
      half8v g;
#pragma unroll
      for (int i = 0; i < 8; i++) g[i] = (half_t)SG[j * 66 + s * 8 + i];
      *(half8v*)(vgc + j * 64 + (s ^ (j & 7)) * 8) = g;
    }
    WAIT_LGKM_BAR();

    // ---- Y: Y[j][r] = G~_j @ E' + u_j @ T' ; y -> SG flat ----
    acc[0] = (floatx4){0.f, 0.f, 0.f, 0.f};
    acc[1] = (floatx4){0.f, 0.f, 0.f, 0.f};
#pragma unroll
    for (int ks = 0; ks < 2; ks++) {
      half8v ag = LDF(vgc, mi * 16 + lrow, ks, lrow & 7);
      half8v au = LDF(uh, mi * 16 + lrow, ks, lrow & 7);
#pragma unroll
      for (int tt = 0; tt < 2; tt++) {
        int rb = (ri0 + tt * 2) * 16 + lrow;
        half8v be = LDF(tE, rb, ks, lrow & 7);
        half8v bt = LDF(tT, rb, ks, lrow & 7);
        acc[tt] = __builtin_amdgcn_mfma_f32_16x16x32_f16(ag, be, acc[tt], 0, 0, 0);
        acc[tt] = __builtin_amdgcn_mfma_f32_16x16x32_f16(au, bt, acc[tt], 0, 0, 0);
      }
    }
#pragma unroll
    for (int tt = 0; tt < 2; tt++) {
#pragma unroll
      for (int reg = 0; reg < 4; reg++) {
        int j = mi * 16 + 4 * lg + reg;
        int r = (ri0 + tt * 2) * 16 + lrow;
        int cph = (((r >> 3) ^ (j & 7)) << 3) + (r & 7);
        SG[j * 64 + r] = acc[tt][reg] + sD4 * (float)uh[j * 64 + cph];
      }
    }
    WAIT_LGKM_BAR();

    // ---- final coalesced pass: out = q * y ----
    {
      size_t bh = (size_t)(bi * 512 + h) * 2048;
      half8v qv = *(const half8v*)(qbuf + bh + tid * 8);
      float* op = outp + bh;
      float4 o0, o1;
      o0.x = (float)qv[0] * SG[tid * 8 + 0];
      o0.y = (float)qv[1] * SG[tid * 8 + 1];
      o0.z = (float)qv[2] * SG[tid * 8 + 2];
      o0.w = (float)qv[3] * SG[tid * 8 + 3];
      o1.x = (float)qv[4] * SG[tid * 8 + 4];
      o1.y = (float)qv[5] * SG[tid * 8 + 5];
      o1.z = (float)qv[6] * SG[tid * 8 + 6];
      o1.w = (float)qv[7] * SG[tid * 8 + 7];
      *(float4*)(op + tid * 8) = o0;
      *(float4*)(op + tid * 8 + 4) = o1;
    }
    WAIT_LGKM_BAR();   // y (SG) fully consumed before next batch overwrites
    cur ^= 1;
  }
#undef LDF
}

// ---------------------------------------------------------------------------
extern "C" void kernel_launch(void* const* d_in, const int* in_sizes, int n_in,
                              void* d_out, int out_size, void* d_ws, size_t ws_size,
                              hipStream_t stream) {
  const float* x      = (const float*)d_in[0];
  const float* Wq     = (const float*)d_in[1];
  const float* bq     = (const float*)d_in[2];
  const float* Wk     = (const float*)d_in[3];
  const float* bk     = (const float*)d_in[4];
  const float* Wv     = (const float*)d_in[5];
  const float* bv     = (const float*)d_in[6];
  const float* shC    = (const float*)d_in[7];
  const float* shD    = (const float*)d_in[8];
  const float* log_dt = (const float*)d_in[9];
  const float* A_real = (const float*)d_in[10];
  const float* A_imag = (const float*)d_in[11];
  const float* C_re   = (const float*)d_in[12];
  const float* C_im   = (const float*)d_in[13];
  const float* s4D    = (const float*)d_in[14];
  float* out = (float*)d_out;
  half_t* wsh = (half_t*)d_ws;

  half_t* qbuf = wsh;                         // 8388608 halfs (linear)
  half_t* kbuf = wsh + 8388608;               // 8388608 (swizzled image)
  half_t* vbuf = wsh + 16777216;              // 8388608 (swizzled image)
  half_t* xT16 = wsh + 25165824;              // 8388608
  half_t* W16  = wsh + 33554432;              // 786432
  half_t* Vt   = wsh + 34340864;              // 2097152 (swizzled image)
  half_t* Et   = wsh + 36438016;              // 2097152
  half_t* Tt   = wsh + 38535168;              // 2097152
  half_t* T1t  = wsh + 40632320;              // 2097152
  half_t* T2t  = wsh + 42729472;              // 2097152
  float*  wt2  = (float*)(wsh + 44826624);    // 32768 f32

  prep<<<3072, 256, 0, stream>>>(x, Wq, Wk, Wv, log_dt, A_real, A_imag,
                                 C_re, C_im, shC, xT16, W16,
                                 Vt, Et, Tt, T1t, T2t, wt2);
  gemm_qkv<<<dim3(1536), 256, 0, stream>>>(xT16, W16, bq, bk, bv,
                                           qbuf, kbuf, vbuf);
  s4d_main<<<512, 256, 0, stream>>>(kbuf, vbuf, T1t, T2t, Vt, Et, Tt,
                                    wt2, shD, s4D, qbuf, out);
}

// Round 9
// 84.749 us; speedup vs baseline: 1.1715x; 1.0163x over previous
//
#include <hip/hip_runtime.h>
#include <cstdint>

// ---------------------------------------------------------------------------
// H3 block: out = q * S4D( v * Shift(k) ),  q/k/v = W{q,k,v} @ x + b
// prep   : transpose x -> (b,l,d) f16  |  convert W -> f16   (concurrent)
// gemm   : merged M=1536 x N=16384 x K=512, 128x128, BK=64, gload_lds(16B),
//          swizzled ds_read_b128, LDS epilogue -> coalesced half8 stores
// s4d    : one block per head h (512 blocks, 2/CU resident), 8-batch loop;
//          all 5 64x64 tables COMPUTED IN-BLOCK into LDS (no global tables);
//          k/v double-buffered one batch ahead, counted vmcnt(2);
//          scan emits f16 G~ directly (no separate convert phase);
//          5 raw barriers per batch, no drains in the loop.
// Swizzle: within a 64-half row R, 16B slot s -> s ^ (R&7).
// ---------------------------------------------------------------------------

#define DMODEL 512
#define LSEQ 2048

typedef _Float16 half_t;
typedef __attribute__((ext_vector_type(2))) _Float16 half2v;
typedef __attribute__((ext_vector_type(4))) _Float16 half4v;
typedef __attribute__((ext_vector_type(8))) _Float16 half8v;
typedef __attribute__((ext_vector_type(4))) float floatx4;

#define SW(R, c) ((R) * 64 + ((((c) >> 3) ^ ((R) & 7)) << 3) + ((c) & 7))

__device__ __forceinline__ void gload_lds16(const half_t* g, half_t* l) {
  __builtin_amdgcn_global_load_lds(
      (const __attribute__((address_space(1))) uint32_t*)g,
      (__attribute__((address_space(3))) uint32_t*)l, 16, 0, 0);
}

#define WAIT_LGKM_BAR()                                   \
  do {                                                    \
    asm volatile("s_waitcnt lgkmcnt(0)" ::: "memory");    \
    __builtin_amdgcn_s_barrier();                         \
    __builtin_amdgcn_sched_barrier(0);                    \
  } while (0)

// ---------------- prep: transpose x | convert W ----------------------------
__global__ __launch_bounds__(256) void prep(
    const float* __restrict__ x, const float* __restrict__ Wq,
    const float* __restrict__ Wk, const float* __restrict__ Wv,
    half_t* __restrict__ xT, half_t* __restrict__ W16) {
  __shared__ float tile[64][68];
  int bid = blockIdx.x;
  int tid = threadIdx.x;
  if (bid < 2048) {
    // ---------------- transpose x (64x64 tiles) ----------------
    int b = bid >> 8, rem = bid & 255;
    int d0 = (rem >> 5) * 64, l0 = (rem & 31) * 64;
    int dy = tid >> 4, lx = tid & 15;
    const float* xp = x + ((size_t)(b * 512 + d0)) * 2048 + l0;
#pragma unroll
    for (int rr = 0; rr < 4; rr++) {
      float4 v = *(const float4*)(xp + (size_t)(rr * 16 + dy) * 2048 + lx * 4);
      *(float4*)&tile[rr * 16 + dy][lx * 4] = v;
    }
    __syncthreads();
    half_t* op = xT + ((size_t)(b * 2048 + l0)) * 512 + d0;
    int lr = tid >> 2, c4 = tid & 3;
#pragma unroll
    for (int cc = 0; cc < 2; cc++) {
      int ch = cc * 4 + c4;
      half8v hv;
#pragma unroll
      for (int e = 0; e < 8; e++) hv[e] = (half_t)tile[ch * 8 + e][lr];
      *(half8v*)(op + (size_t)lr * 512 + ch * 8) = hv;
    }
  } else {
    // ---------------- convert W (grid-stride x6) ----------------
    int base = (bid - 2048) * 256 + tid;
#pragma unroll
    for (int it = 0; it < 6; it++) {
      int i = base + it * 131072;
      const float* src = (i < 262144) ? Wq : ((i < 524288) ? Wk : Wv);
      W16[i] = (half_t)src[i & 262143];
    }
  }
}

// ---------------- merged qkv GEMM (128x128, BK=64, LDS epilogue) -----------
__global__ __launch_bounds__(256) void gemm_qkv(
    const half_t* __restrict__ xT, const half_t* __restrict__ Wstk,
    const float* __restrict__ bq, const float* __restrict__ bk,
    const float* __restrict__ bv, half_t* __restrict__ outq,
    half_t* __restrict__ outk, half_t* __restrict__ outv) {
  __shared__ half_t smem[16384];   // As 8192 | Bs 8192; reused as C 128x128
  half_t* As = smem;
  half_t* Bs = smem + 8192;
  int flat = blockIdx.x;                         // 1536 = 8 xcd x 192
  int swz = (flat & 7) * 192 + (flat >> 3);      // XCD chunk swizzle
  int nt = swz / 12, mt = swz - nt * 12;
  int n0 = nt * 128, m0 = mt * 128;
  int tid = threadIdx.x;
  int lane = tid & 63, wid = tid >> 6;
  int wr = wid >> 1, wc = wid & 1;
  int lrow = lane & 15, lg = lane >> 4;
  int rsub = lane >> 3, ssub = lane & 7;
  int gslot = ssub ^ rsub;                       // inverse-swizzled source slot

  floatx4 acc[4][4];
#pragma unroll
  for (int i = 0; i < 4; i++)
#pragma unroll
    for (int j = 0; j < 4; j++) acc[i][j] = (floatx4){0.f, 0.f, 0.f, 0.f};

  const half_t* gA = Wstk + (size_t)(m0 + wid * 32 + rsub) * 512 + gslot * 8;
  const half_t* gB = xT + (size_t)(n0 + wid * 32 + rsub) * 512 + gslot * 8;

  for (int kk = 0; kk < 512; kk += 64) {
#pragma unroll
    for (int i = 0; i < 4; i++) {
      int c = wid * 4 + i;                       // 1KB chunk, rows c*8..c*8+7
      gload_lds16(gA + (size_t)i * 8 * 512 + kk, As + c * 512);
      gload_lds16(gB + (size_t)i * 8 * 512 + kk, Bs + c * 512);
    }
    __syncthreads();
#pragma unroll
    for (int h = 0; h < 2; h++) {
      half8v af[4], bf[4];
#pragma unroll
      for (int i = 0; i < 4; i++) {
        int r = wr * 64 + i * 16 + lrow;
        af[i] = *(const half8v*)(As + r * 64 + ((h * 4 + lg) ^ (r & 7)) * 8);
      }
#pragma unroll
      for (int j = 0; j < 4; j++) {
        int r = wc * 64 + j * 16 + lrow;
        bf[j] = *(const half8v*)(Bs + r * 64 + ((h * 4 + lg) ^ (r & 7)) * 8);
      }
#pragma unroll
      for (int i = 0; i < 4; i++)
#pragma unroll
        for (int j = 0; j < 4; j++)
          acc[i][j] = __builtin_amdgcn_mfma_f32_16x16x32_f16(af[i], bf[j],
                                                             acc[i][j], 0, 0, 0);
    }
    __syncthreads();
  }

  // ---- epilogue via LDS: frags -> swizzled C tile -> coalesced stores ----
  int z = m0 >> 9;                               // uniform per block
  const float* bias = (z == 0) ? bq : ((z == 1) ? bk : bv);
  half_t* smemC = smem;                          // 128 x 128 halfs, slot^=(d&15)
#pragma unroll
  for (int i = 0; i < 4; i++) {
    int dl = wr * 64 + i * 16 + 4 * lg;
    float4 b4 = *(const float4*)&bias[(m0 + dl) & 511];
#pragma unroll
    for (int j = 0; j < 4; j++) {
      int ll = wc * 64 + j * 16 + lrow;
#pragma unroll
      for (int reg = 0; reg < 4; reg++) {
        int d = dl + reg;
        float val = acc[i][j][reg] + ((const float*)&b4)[reg];
        smemC[d * 128 + (((ll >> 3) ^ (d & 15)) << 3) + (ll & 7)] = (half_t)val;
      }
    }
  }
  __syncthreads();
  {
    int t4 = tid >> 4, ch = tid & 15;
    int b = n0 >> 11, l0 = n0 & 2047;
    half_t* outp = (z == 0) ? outq : ((z == 1) ? outk : outv);
#pragma unroll
    for (int rep = 0; rep < 8; rep++) {
      int d = rep * 16 + t4;
      half8v v = *(const half8v*)(smemC + d * 128 + ((ch ^ (d & 15)) << 3));
      size_t rowb = ((size_t)(b * 512 + ((m0 + d) & 511))) * 2048;
      if (z == 0) {
        *(half8v*)(outp + rowb + l0 + ch * 8) = v;       // q: linear
      } else {                                            // k,v: swizzled image
        int j = (l0 >> 6) + (ch >> 3);
        int s = ch & 7;
        *(half8v*)(outp + rowb + j * 64 + ((s ^ (j & 7)) << 3)) = v;
      }
    }
  }
}

// ---------------- fused Shift + S4D per head, 8-batch loop -----------------
__global__ __launch_bounds__(256) void s4d_main(
    const half_t* __restrict__ kimg, const half_t* __restrict__ vimg,
    const float* __restrict__ shC, const float* __restrict__ log_dt,
    const float* __restrict__ A_real, const float* __restrict__ A_imag,
    const float* __restrict__ C_re, const float* __restrict__ C_im,
    const float* __restrict__ shD, const float* __restrict__ s4D,
    const half_t* __restrict__ qbuf, float* __restrict__ outp) {
  __shared__ half_t tabs[5][4096];  // 0:T1 1:T2 2:V 3:E 4:T (built in-block)
  __shared__ half_t kl[2][33 * 64]; // row 0 zeros; row 1+j = k chunk j
  __shared__ half_t vg[2][32 * 64]; // v, later G~ (f16)
  __shared__ half_t uh[32 * 64];    // u = v * shift(k)
  __shared__ float SG[32 * 66];     // S states / flat y; prologue scratch
  int h = blockIdx.x;
  int tid = threadIdx.x;
  int lane = tid & 63, wid = tid >> 6;
  int lrow = lane & 15, lg = lane >> 4;
  int mi = wid & 1, ri0 = wid >> 1;

  // ---- issue batch-0 k/v gloads first (latency hides under table build) --
  gload_lds16(kimg + (size_t)h * 2048 + wid * 512 + lane * 8,
              &kl[0][64 + wid * 512]);
  gload_lds16(vimg + (size_t)h * 2048 + wid * 512 + lane * 8,
              &vg[0][wid * 512]);
  if (tid < 16) {
    half8v zz = {(_Float16)0, (_Float16)0, (_Float16)0, (_Float16)0,
                 (_Float16)0, (_Float16)0, (_Float16)0, (_Float16)0};
    *(half8v*)(&kl[tid >> 3][(tid & 7) * 8]) = zz;
  }

  // ---- build the 5 tables in LDS (scratch overlays SG) ----
  float* Kt   = SG;         // [64]
  float* tapl = SG + 64;    // [64]
  float* aL   = SG + 128;   // [32] each
  float* bL   = SG + 160;
  float* wrL  = SG + 192;
  float* wiL  = SG + 224;
  float* crL  = SG + 256;
  float* ciL  = SG + 288;
  if (tid < 64) { Kt[tid] = 0.f; tapl[tid] = shC[h * 64 + tid]; }
  if (tid < 32) {
    int n = tid, hn = h * 32 + n;
    float dt = expf(log_dt[h]);
    float Ar = -expf(A_real[hn]), Ai = A_imag[hn];
    float a = dt * Ar, b = dt * Ai;
    float ea = expf(a);
    float wr = ea * cosf(b), wi = ea * sinf(b);
    float Am2 = Ar * Ar + Ai * Ai;
    float zr = wr - 1.0f, zi = wi;
    float qr = (zr * Ar + zi * Ai) / Am2;
    float qi = (zi * Ar - zr * Ai) / Am2;
    aL[n] = a; bL[n] = b; wrL[n] = wr; wiL[n] = wi;
    crL[n] = C_re[hn] * qr - C_im[hn] * qi;
    ciL[n] = C_re[hn] * qi + C_im[hn] * qr;
  }
  __syncthreads();
  float wTr, wTi;                    // scan constants (used by tid<32)
  {
    int n = tid & 31;
    float e64 = expf(64.f * aL[n]);
    float b64 = 64.f * bL[n];
    wTr = e64 * cosf(b64);
    wTi = e64 * sinf(b64);
  }
  {
    int r = tid >> 2, nb = (tid & 3) * 8;
    float ksum = 0.f;
#pragma unroll
    for (int i = 0; i < 8; i++) {
      int n = nb + i;
      float a = aL[n], b = bL[n];
      float cr = crL[n], ci = ciL[n];
      float er = expf(a * (float)r);
      float w0r = er * cosf(b * (float)r), w0i = er * sinf(b * (float)r);
      ksum += 2.f * (cr * w0r - ci * w0i);
      float wr = wrL[n], wi = wiL[n];
      float w1r = w0r * wr - w0i * wi, w1i = w0r * wi + w0i * wr;
      tabs[3][SW(r, 2 * n)]     = (half_t)(2.f * (cr * w1r - ci * w1i));
      tabs[3][SW(r, 2 * n + 1)] = (half_t)(-2.f * (cr * w1i + ci * w1r));
      tabs[2][SW(2 * n, 63 - r)]     = (half_t)w0r;
      tabs[2][SW(2 * n + 1, 63 - r)] = (half_t)w0i;
    }
    atomicAdd(&Kt[r], ksum);
  }
  __syncthreads();
#pragma unroll
  for (int e = 0; e < 16; e++) {
    int idx = e * 256 + tid;
    int r = idx >> 6, t = idx & 63;
    int d = r - t;
    int a = SW(r, t);
    tabs[4][a] = (d >= 0) ? (half_t)Kt[d] : (half_t)0.f;
    tabs[0][a] = (d >= 0) ? (half_t)tapl[d] : (half_t)0.f;
    tabs[1][a] = (d < 0) ? (half_t)tapl[64 + d] : (half_t)0.f;
  }
  float sDsh = shD[h];
  float sD4 = s4D[h];
  const half_t* t1 = tabs[0];
  const half_t* t2 = tabs[1];
  const half_t* tV = tabs[2];
  const half_t* tE = tabs[3];
  const half_t* tT = tabs[4];

#define LDF(base, r, ks, key) \
  (*(const half8v*)((base) + (r) * 64 + (((ks) * 4 + lg) ^ (key)) * 8))

  int cur = 0;
  for (int bi = 0; bi < 8; bi++) {
    // issue next batch's k/v, then counted wait for current (+ table writes)
    if (bi < 7) {
      size_t nb = (size_t)((bi + 1) * 512 + h) * 2048;
      gload_lds16(kimg + nb + wid * 512 + lane * 8, &kl[cur ^ 1][64 + wid * 512]);
      gload_lds16(vimg + nb + wid * 512 + lane * 8, &vg[cur ^ 1][wid * 512]);
      asm volatile("s_waitcnt vmcnt(2) lgkmcnt(0)" ::: "memory");
    } else {
      asm volatile("s_waitcnt vmcnt(0) lgkmcnt(0)" ::: "memory");
    }
    __builtin_amdgcn_s_barrier();
    __builtin_amdgcn_sched_barrier(0);

    const half_t* klc = kl[cur];
    half_t* vgc = vg[cur];
    floatx4 acc[2];

    // ---- shift: shift[j][r] = k_j @ T1' + k_{j-1} @ T2' ----
    acc[0] = (floatx4){0.f, 0.f, 0.f, 0.f};
    acc[1] = (floatx4){0.f, 0.f, 0.f, 0.f};
    {
      int jA = mi * 16 + lrow;
      int key1 = lrow & 7, key2 = (lrow + 7) & 7;
#pragma unroll
      for (int ks = 0; ks < 2; ks++) {
        half8v a1 = LDF(klc, 1 + jA, ks, key1);
        half8v a2 = LDF(klc, jA, ks, key2);
#pragma unroll
        for (int tt = 0; tt < 2; tt++) {
          int rb = (ri0 + tt * 2) * 16 + lrow;
          half8v b1 = LDF(t1, rb, ks, lrow & 7);
          half8v b2 = LDF(t2, rb, ks, lrow & 7);
          acc[tt] = __builtin_amdgcn_mfma_f32_16x16x32_f16(a1, b1, acc[tt], 0, 0, 0);
          acc[tt] = __builtin_amdgcn_mfma_f32_16x16x32_f16(a2, b2, acc[tt], 0, 0, 0);
        }
      }
    }
    // u = v * (shift + shD*k)
#pragma unroll
    for (int tt = 0; tt < 2; tt++) {
#pragma unroll
      for (int reg = 0; reg < 4; reg++) {
        int j = mi * 16 + 4 * lg + reg;
        int r = (ri0 + tt * 2) * 16 + lrow;
        int cph = (((r >> 3) ^ (j & 7)) << 3) + (r & 7);
        float kvv = (float)klc[(1 + j) * 64 + cph];
        float vvv = (float)vgc[j * 64 + cph];
        uh[j * 64 + cph] = (half_t)(vvv * (acc[tt][reg] + sDsh * kvv));
      }
    }
    WAIT_LGKM_BAR();

    // ---- S phase: S[j][m] = u_j @ V' ----
    acc[0] = (floatx4){0.f, 0.f, 0.f, 0.f};
    acc[1] = (floatx4){0.f, 0.f, 0.f, 0.f};
#pragma unroll
    for (int ks = 0; ks < 2; ks++) {
      half8v a = LDF(uh, mi * 16 + lrow, ks, lrow & 7);
#pragma unroll
      for (int tt = 0; tt < 2; tt++) {
        int rb = (ri0 + tt * 2) * 16 + lrow;
        half8v b = LDF(tV, rb, ks, lrow & 7);
        acc[tt] = __builtin_amdgcn_mfma_f32_16x16x32_f16(a, b, acc[tt], 0, 0, 0);
      }
    }
#pragma unroll
    for (int tt = 0; tt < 2; tt++) {
      int ri = ri0 + tt * 2;
#pragma unroll
      for (int reg = 0; reg < 4; reg++) {
        int j = mi * 16 + 4 * lg + reg;
        SG[j * 66 + ri * 16 + lrow] = acc[tt][reg];
      }
    }
    WAIT_LGKM_BAR();

    // ---- scan (thread n): emit f16 G_{j-1} directly into vgc ----
    if (tid < 32) {
      int n = tid;
      float gr = 0.f, gi = 0.f;
#pragma unroll 4
      for (int j = 0; j < 32; j++) {
        float tr = SG[j * 66 + 2 * n], ti = SG[j * 66 + 2 * n + 1];
        half2v gp = {(half_t)gr, (half_t)gi};
        *(half2v*)(vgc + j * 64 + (((n >> 2) ^ (j & 7)) << 3) + 2 * (n & 3)) = gp;
        float nr = wTr * gr - wTi * gi + tr;
        gi = wTr * gi + wTi * gr + ti;
        gr = nr;
      }
    }
    WAIT_LGKM_BAR();

    // ---- Y: Y[j][r] = G~_j @ E' + u_j @ T' ; y -> SG flat ----
    acc[0] = (floatx4){0.f, 0.f, 0.f, 0.f};
    acc[1] = (floatx4){0.f, 0.f, 0.f, 0.f};
#pragma unroll
    for (int ks = 0; ks < 2; ks++) {
      half8v ag = LDF(vgc, mi * 16 + lrow, ks, lrow & 7);
      half8v au = LDF(uh, mi * 16 + lrow, ks, lrow & 7);
#pragma unroll
      for (int tt = 0; tt < 2; tt++) {
        int rb = (ri0 + tt * 2) * 16 + lrow;
        half8v be = LDF(tE, rb, ks, lrow & 7);
        half8v bt = LDF(tT, rb, ks, lrow & 7);
        acc[tt] = __builtin_amdgcn_mfma_f32_16x16x32_f16(ag, be, acc[tt], 0, 0, 0);
        acc[tt] = __builtin_amdgcn_mfma_f32_16x16x32_f16(au, bt, acc[tt], 0, 0, 0);
      }
    }
#pragma unroll
    for (int tt = 0; tt < 2; tt++) {
#pragma unroll
      for (int reg = 0; reg < 4; reg++) {
        int j = mi * 16 + 4 * lg + reg;
        int r = (ri0 + tt * 2) * 16 + lrow;
        int cph = (((r >> 3) ^ (j & 7)) << 3) + (r & 7);
        SG[j * 64 + r] = acc[tt][reg] + sD4 * (float)uh[j * 64 + cph];
      }
    }
    WAIT_LGKM_BAR();

    // ---- final coalesced pass: out = q * y ----
    {
      size_t bh = (size_t)(bi * 512 + h) * 2048;
      half8v qv = *(const half8v*)(qbuf + bh + tid * 8);
      float* op = outp + bh;
      float4 o0, o1;
      o0.x = (float)qv[0] * SG[tid * 8 + 0];
      o0.y = (float)qv[1] * SG[tid * 8 + 1];
      o0.z = (float)qv[2] * SG[tid * 8 + 2];
      o0.w = (float)qv[3] * SG[tid * 8 + 3];
      o1.x = (float)qv[4] * SG[tid * 8 + 4];
      o1.y = (float)qv[5] * SG[tid * 8 + 5];
      o1.z = (float)qv[6] * SG[tid * 8 + 6];
      o1.w = (float)qv[7] * SG[tid * 8 + 7];
      *(float4*)(op + tid * 8) = o0;
      *(float4*)(op + tid * 8 + 4) = o1;
    }
    // no loop-end barrier: batch-start barrier + barA give >=2-barrier
    // separation for SG reuse; prefetch targets were synced at barE.
    cur ^= 1;
  }
#undef LDF
}

// ---------------------------------------------------------------------------
extern "C" void kernel_launch(void* const* d_in, const int* in_sizes, int n_in,
                              void* d_out, int out_size, void* d_ws, size_t ws_size,
                              hipStream_t stream) {
  const float* x      = (const float*)d_in[0];
  const float* Wq     = (const float*)d_in[1];
  const float* bq     = (const float*)d_in[2];
  const float* Wk     = (const float*)d_in[3];
  const float* bk     = (const float*)d_in[4];
  const float* Wv     = (const float*)d_in[5];
  const float* bv     = (const float*)d_in[6];
  const float* shC    = (const float*)d_in[7];
  const float* shD    = (const float*)d_in[8];
  const float* log_dt = (const float*)d_in[9];
  const float* A_real = (const float*)d_in[10];
  const float* A_imag = (const float*)d_in[11];
  const float* C_re   = (const float*)d_in[12];
  const float* C_im   = (const float*)d_in[13];
  const float* s4D    = (const float*)d_in[14];
  float* out = (float*)d_out;
  half_t* wsh = (half_t*)d_ws;

  half_t* qbuf = wsh;                         // 8388608 halfs (linear)
  half_t* kbuf = wsh + 8388608;               // 8388608 (swizzled image)
  half_t* vbuf = wsh + 16777216;              // 8388608 (swizzled image)
  half_t* xT16 = wsh + 25165824;              // 8388608
  half_t* W16  = wsh + 33554432;              // 786432

  prep<<<2560, 256, 0, stream>>>(x, Wq, Wk, Wv, xT16, W16);
  gemm_qkv<<<dim3(1536), 256, 0, stream>>>(xT16, W16, bq, bk, bv,
                                           qbuf, kbuf, vbuf);
  s4d_main<<<512, 256, 0, stream>>>(kbuf, vbuf, shC, log_dt, A_real, A_imag,
                                    C_re, C_im, shD, s4D, qbuf, out);
}